// Round 1
// baseline (105.552 us; speedup 1.0000x reference)
//
#include <hip/hip_runtime.h>
#include <stdint.h>

// Bit-serial conv2d closed form: g(x,w) = sign(w) * ((x * |w|) >> 4),
// x in [0,15], w in [-8,7].  out = relu(bias + sum_{3x3,c} g).
// B=4 H=32 W=32 C=64 F=128.

#define NW 73728   // 9*64*128 weights

__global__ __launch_bounds__(256) void prep_w(const float* __restrict__ kern,
                                              uint8_t* __restrict__ wabs,
                                              int8_t* __restrict__ wsgn) {
    int tid = blockIdx.x * 256 + threadIdx.x;
    if (tid >= NW) return;
    // dest layout: [ki][f][c]  (c contiguous so 4 c pack per dword)
    int c  = tid & 63;
    int kf = tid >> 6;        // ki*128 + f
    int f  = kf & 127;
    int ki = kf >> 7;
    float w = kern[(ki * 64 + c) * 128 + f];   // src layout [ki][c][f]
    int wi = (int)w;
    int m  = wi < 0 ? -wi : wi;
    wabs[tid] = (uint8_t)m;
    wsgn[tid] = (int8_t)((wi > 0) - (wi < 0));
}

__global__ __launch_bounds__(256) void conv_main(const float* __restrict__ input,
                                                 const uint8_t* __restrict__ wabs,
                                                 const int8_t* __restrict__ wsgn,
                                                 const float* __restrict__ bias,
                                                 float* __restrict__ out) {
    // blockIdx.x = ((b*32 + h)*4 + wblk); block covers 8 w-positions x 128 f
    int bid  = blockIdx.x;
    int wblk = bid & 3;
    int h    = (bid >> 2) & 31;
    int b    = bid >> 7;
    int tid  = threadIdx.x;
    int f    = tid & 127;
    int wg   = tid >> 7;       // wave-uniform: waves 0,1 -> wg0; waves 2,3 -> wg1
    int w0   = wblk * 8;

    // patch[r][col][c], c contiguous -> ds_read_b128 fetches 4 c, broadcast across wave
    __shared__ int patch[3 * 10 * 64];

    for (int idx = tid; idx < 3 * 10 * 64; idx += 256) {
        int c   = idx & 63;
        int rc  = idx >> 6;      // r*10 + col
        int r   = rc / 10;
        int col = rc - r * 10;
        int gh  = h + r - 1;
        int gw  = w0 + col - 1;
        int v = 0;
        if ((unsigned)gh < 32u && (unsigned)gw < 32u)
            v = (int)input[(((b * 32) + gh) * 32 + gw) * 64 + c];
        patch[idx] = v;
    }
    __syncthreads();

    int acc0 = 0, acc1 = 0, acc2 = 0, acc3 = 0;
    int colbase = wg * 4;        // thread handles output cols w0+colbase+{0..3}

    for (int i = 0; i < 3; ++i) {
        for (int j = 0; j < 3; ++j) {
            int ki = i * 3 + j;
            const uint8_t* wa  = wabs + (ki * 128 + f) * 64;
            const int8_t*  wsg = wsgn + (ki * 128 + f) * 64;
            const int*     prw = patch + (i * 10 + colbase + j) * 64;
            #pragma unroll 4
            for (int c4 = 0; c4 < 16; ++c4) {
                uint32_t ma = *(const uint32_t*)(wa  + c4 * 4);
                uint32_t sg = *(const uint32_t*)(wsg + c4 * 4);
                const int* p0 = prw + c4 * 4;
                int4 x0 = *(const int4*)(p0);          // output t=0, 4 c values
                int4 x1 = *(const int4*)(p0 + 64);     // t=1 (next col)
                int4 x2 = *(const int4*)(p0 + 128);    // t=2
                int4 x3 = *(const int4*)(p0 + 192);    // t=3
                #pragma unroll
                for (int e = 0; e < 4; ++e) {
                    int m = (int)((ma >> (8 * e)) & 15u);         // |w| <= 8
                    int s = (int)((int8_t)(sg >> (8 * e)));       // sign in {-1,0,1}
                    int a0 = ((&x0.x)[e] & 15);   // &15: known-bits -> mul24
                    int a1 = ((&x1.x)[e] & 15);
                    int a2 = ((&x2.x)[e] & 15);
                    int a3 = ((&x3.x)[e] & 15);
                    acc0 += ((a0 * m) >> 4) * s;
                    acc1 += ((a1 * m) >> 4) * s;
                    acc2 += ((a2 * m) >> 4) * s;
                    acc3 += ((a3 * m) >> 4) * s;
                }
            }
        }
    }

    int bi = (int)bias[f];
    int rowbase = ((b * 32 + h) * 32);
    {
        int r0 = acc0 + bi; r0 = r0 < 0 ? 0 : r0;
        int r1 = acc1 + bi; r1 = r1 < 0 ? 0 : r1;
        int r2 = acc2 + bi; r2 = r2 < 0 ? 0 : r2;
        int r3 = acc3 + bi; r3 = r3 < 0 ? 0 : r3;
        int wbase = w0 + colbase;
        out[(rowbase + wbase + 0) * 128 + f] = (float)r0;
        out[(rowbase + wbase + 1) * 128 + f] = (float)r1;
        out[(rowbase + wbase + 2) * 128 + f] = (float)r2;
        out[(rowbase + wbase + 3) * 128 + f] = (float)r3;
    }
}

extern "C" void kernel_launch(void* const* d_in, const int* in_sizes, int n_in,
                              void* d_out, int out_size, void* d_ws, size_t ws_size,
                              hipStream_t stream) {
    const float* input  = (const float*)d_in[0];   // [4,32,32,64]
    const float* kernel = (const float*)d_in[1];   // [3,3,64,128]
    const float* bias   = (const float*)d_in[2];   // [128]
    // d_in[3] = bits (==4, hard-coded in the closed form)

    uint8_t* wabs = (uint8_t*)d_ws;
    int8_t*  wsgn = (int8_t*)d_ws + NW;

    prep_w<<<(NW + 255) / 256, 256, 0, stream>>>(kernel, wabs, wsgn);
    conv_main<<<512, 256, 0, stream>>>(input, wabs, wsgn, bias, (float*)d_out);
}

// Round 2
// 91.318 us; speedup vs baseline: 1.1559x; 1.1559x over previous
//
#include <hip/hip_runtime.h>
#include <stdint.h>

// Bit-serial conv2d closed form: term = sign(w) * ((x * |w|) >> 4)
//                                     = (x * w + A) >> 4   [arith shift]
// where A = (w<0) ? 15 : 0, since -(a>>4) == (15-a)>>4 for a>=0.
// x in [0,15], w in [-8,7].  out = relu(bias + sum_{3x3,c} term).
// B=4 H=32 W=32 C=64 F=128.  All math exact in i16 (|acc| <= 4032).

typedef short s16x2 __attribute__((ext_vector_type(2)));

#define NW2 36864   // 9*8*128*4 packed dwords (2 i16 weights each)

// Pack weights: dword index = ((ki*8 + c8)*128 + f)*4 + e
// holds channels c = c8*8 + e*2 and c+1 as two i16 halves.
// -> lane f's dwordx4 load of [e=0..3] is coalesced across the wave.
__global__ __launch_bounds__(256) void prep_w(const float* __restrict__ kern,
                                              uint32_t* __restrict__ wpk) {
    int tid = blockIdx.x * 256 + threadIdx.x;
    if (tid >= NW2) return;
    int e   = tid & 3;
    int f   = (tid >> 2) & 127;
    int c8  = (tid >> 9) & 7;
    int ki  = tid >> 12;
    int c   = c8 * 8 + e * 2;
    int wlo = (int)kern[(ki * 64 + c    ) * 128 + f];
    int whi = (int)kern[(ki * 64 + c + 1) * 128 + f];
    wpk[tid] = (uint32_t)(uint16_t)(int16_t)wlo |
               ((uint32_t)(uint16_t)(int16_t)whi << 16);
}

__global__ __launch_bounds__(128, 4) void conv_main(const float* __restrict__ input,
                                                    const uint32_t* __restrict__ wpk,
                                                    const float* __restrict__ bias,
                                                    float* __restrict__ out) {
    // 1024 blocks: bid = ((b*32 + h)*8 + wblk); block = 4 output cols x 128 f
    int bid  = blockIdx.x;
    int wblk = bid & 7;
    int h    = (bid >> 3) & 31;
    int b    = bid >> 8;
    int tid  = threadIdx.x;     // == f
    int w0   = wblk * 4;

    // patch2[r][col][c2]: 3 rows x 6 cols x 32 dwords (2 channels per dword)
    __shared__ int patch2[3 * 6 * 32];

    for (int idx = tid; idx < 3 * 6 * 32; idx += 128) {
        int c2  = idx & 31;
        int rc  = idx >> 5;
        int r   = rc / 6;
        int col = rc - r * 6;
        int gh  = h + r - 1;
        int gw  = w0 + col - 1;
        int v = 0;
        if ((unsigned)gh < 32u && (unsigned)gw < 32u) {
            const float* p = &input[(((b * 32) + gh) * 32 + gw) * 64 + c2 * 2];
            float2 xf = *(const float2*)p;
            v = (int)xf.x | ((int)xf.y << 16);
        }
        patch2[idx] = v;
    }
    __syncthreads();

    s16x2 acc0 = {0, 0}, acc1 = {0, 0}, acc2 = {0, 0}, acc3 = {0, 0};

    #pragma unroll
    for (int i = 0; i < 3; ++i) {
        #pragma unroll
        for (int j = 0; j < 3; ++j) {
            int ki = i * 3 + j;
            const uint32_t* wrow = wpk + (size_t)(ki * 8) * 512 + tid * 4;
            const int* prw = patch2 + (i * 6 + j) * 32;
            for (int c8 = 0; c8 < 8; ++c8) {
                int4 wv = *(const int4*)(wrow + c8 * 512);     // coalesced, L2-hot
                int4 x0 = *(const int4*)(prw + c8 * 4);        // ds_read_b128 bcast
                int4 x1 = *(const int4*)(prw + c8 * 4 + 32);
                int4 x2 = *(const int4*)(prw + c8 * 4 + 64);
                int4 x3 = *(const int4*)(prw + c8 * 4 + 96);
                #pragma unroll
                for (int e = 0; e < 4; ++e) {
                    s16x2 w2 = __builtin_bit_cast(s16x2, (&wv.x)[e]);
                    s16x2 A  = (w2 >> 15) & (short)15;         // 15 where w<0
                    s16x2 t;
                    t = (__builtin_bit_cast(s16x2, (&x0.x)[e]) * w2 + A) >> 4; acc0 += t;
                    t = (__builtin_bit_cast(s16x2, (&x1.x)[e]) * w2 + A) >> 4; acc1 += t;
                    t = (__builtin_bit_cast(s16x2, (&x2.x)[e]) * w2 + A) >> 4; acc2 += t;
                    t = (__builtin_bit_cast(s16x2, (&x3.x)[e]) * w2 + A) >> 4; acc3 += t;
                }
            }
        }
    }

    int bi = (int)bias[tid];
    int rowbase = (b * 32 + h) * 32 + w0;
    int a;
    a = __builtin_bit_cast(int, acc0);
    { int r0 = (int)(short)a + (a >> 16) + bi; out[(rowbase + 0) * 128 + tid] = (float)(r0 < 0 ? 0 : r0); }
    a = __builtin_bit_cast(int, acc1);
    { int r1 = (int)(short)a + (a >> 16) + bi; out[(rowbase + 1) * 128 + tid] = (float)(r1 < 0 ? 0 : r1); }
    a = __builtin_bit_cast(int, acc2);
    { int r2 = (int)(short)a + (a >> 16) + bi; out[(rowbase + 2) * 128 + tid] = (float)(r2 < 0 ? 0 : r2); }
    a = __builtin_bit_cast(int, acc3);
    { int r3 = (int)(short)a + (a >> 16) + bi; out[(rowbase + 3) * 128 + tid] = (float)(r3 < 0 ? 0 : r3); }
}

extern "C" void kernel_launch(void* const* d_in, const int* in_sizes, int n_in,
                              void* d_out, int out_size, void* d_ws, size_t ws_size,
                              hipStream_t stream) {
    const float* input  = (const float*)d_in[0];   // [4,32,32,64]
    const float* kernel = (const float*)d_in[1];   // [3,3,64,128]
    const float* bias   = (const float*)d_in[2];   // [128]
    // d_in[3] = bits (==4, baked into the closed form)

    uint32_t* wpk = (uint32_t*)d_ws;               // 147456 B

    prep_w<<<(NW2 + 255) / 256, 256, 0, stream>>>(kernel, wpk);
    conv_main<<<1024, 128, 0, stream>>>(input, wpk, bias, (float*)d_out);
}

// Round 3
// 80.972 us; speedup vs baseline: 1.3036x; 1.1278x over previous
//
#include <hip/hip_runtime.h>
#include <stdint.h>

// Bit-serial conv2d closed form: term = sign(w) * ((x * |w|) >> 4)
//                                     = (x * w + A) >> 4   [arith shift]
// where A = (w<0) ? 15 : 0, since -(a>>4) == (15-a)>>4 for a>=0.
// x in [0,15], w in [-8,7].  out = relu(bias + sum_{3x3,c} term).
// B=4 H=32 W=32 C=64 F=128.  Exact in i16 (|acc| <= 4032).

typedef short s16x2 __attribute__((ext_vector_type(2)));

#define NWPK 36864            // 9*8*128*4 packed weight dwords (2 i16 each)
#define XOFF 36864            // dword offset of padded x in ws
#define NXPK 147968           // 4*34*34*32 padded input dwords (2 i16 each)

// One prep launch: blocks [0,144) pack weights, [144, 722) pack+pad input.
__global__ __launch_bounds__(256) void prep_all(const float* __restrict__ kern,
                                                const float* __restrict__ input,
                                                uint32_t* __restrict__ ws) {
    int bid = blockIdx.x, tid = threadIdx.x;
    if (bid < 144) {
        int t  = bid * 256 + tid;            // < 36864
        int e  = t & 3;
        int f  = (t >> 2) & 127;
        int c8 = (t >> 9) & 7;
        int ki = t >> 12;
        int c  = c8 * 8 + e * 2;
        int wlo = (int)kern[(ki * 64 + c    ) * 128 + f];   // kernel [ki][c][f]
        int whi = (int)kern[(ki * 64 + c + 1) * 128 + f];
        ws[t] = (uint32_t)(uint16_t)(int16_t)wlo |
                ((uint32_t)(uint16_t)(int16_t)whi << 16);
    } else {
        int t = (bid - 144) * 256 + tid;     // < 147968
        if (t >= NXPK) return;
        int c2    = t & 31;
        int rest  = t >> 5;                  // b*34*34 + hp*34 + wp
        int wp    = rest % 34;
        int rest2 = rest / 34;
        int hp    = rest2 % 34;
        int b     = rest2 / 34;
        int v = 0;
        if (hp >= 1 && hp <= 32 && wp >= 1 && wp <= 32) {
            const float* p = &input[(((b * 32) + hp - 1) * 32 + (wp - 1)) * 64 + c2 * 2];
            v = (int)p[0] | ((int)p[1] << 16);
        }
        ws[XOFF + t] = (uint32_t)v;
    }
}

// 2048 blocks x 128 threads; block = (b, h, wpair) -> 2 output cols x 128 f.
// Each thread: 2 outputs. 4096 waves -> 16 waves/CU (4/SIMD).
__global__ __launch_bounds__(128, 4) void conv_main(const uint32_t* __restrict__ ws,
                                                    const float* __restrict__ bias,
                                                    float* __restrict__ out) {
    const uint32_t* wpk = ws;
    const uint32_t* xpk = ws + XOFF;

    int bid   = blockIdx.x;
    int wpair = bid & 15;
    int h     = (bid >> 4) & 31;
    int b     = bid >> 9;
    int f     = threadIdx.x;      // 0..127
    int w0    = wpair * 2;

    // patch[r][col][c2]: 3 rows x 4 padded cols x 32 dwords (2 ch each)
    __shared__ uint32_t patch[3 * 4 * 32];

    #pragma unroll
    for (int k = 0; k < 3; ++k) {
        int idx  = k * 128 + f;
        int c2   = idx & 31;
        int colr = idx >> 5;
        int col  = colr & 3;
        int r    = colr >> 2;
        patch[idx] = xpk[((b * 34 + h + r) * 34 + (w0 + col)) * 32 + c2];
    }
    __syncthreads();

    s16x2 acc0 = {0, 0}, acc1 = {0, 0};

    for (int i = 0; i < 3; ++i) {
        for (int j = 0; j < 3; ++j) {
            int ki = i * 3 + j;
            const uint32_t* wrow = wpk + (ki * 1024 + f) * 4;   // (ki*8)*128*4 + f*4
            const uint32_t* px   = patch + (i * 4 + j) * 32;
            #pragma unroll
            for (int c8 = 0; c8 < 8; ++c8) {
                int4 wv = *(const int4*)(wrow + c8 * 512);   // coalesced 1KB/wave, L1/L2-hot
                int4 x0 = *(const int4*)(px + c8 * 4);       // ds_read_b128 broadcast
                int4 x1 = *(const int4*)(px + 32 + c8 * 4);  // next col (pixel 1)
                #pragma unroll
                for (int e = 0; e < 4; ++e) {
                    s16x2 w2 = __builtin_bit_cast(s16x2, (&wv.x)[e]);
                    s16x2 A  = (w2 >> 15) & (short)15;       // 15 where w<0
                    s16x2 t0 = (__builtin_bit_cast(s16x2, (&x0.x)[e]) * w2 + A) >> 4;
                    s16x2 t1 = (__builtin_bit_cast(s16x2, (&x1.x)[e]) * w2 + A) >> 4;
                    acc0 += t0;
                    acc1 += t1;
                }
            }
        }
    }

    int bi   = (int)bias[f];
    int base = ((b * 32 + h) * 32 + w0) * 128 + f;
    int a;
    a = __builtin_bit_cast(int, acc0);
    { int r0 = (int)(short)(a & 0xffff) + (a >> 16) + bi;
      out[base]       = (float)(r0 < 0 ? 0 : r0); }
    a = __builtin_bit_cast(int, acc1);
    { int r1 = (int)(short)(a & 0xffff) + (a >> 16) + bi;
      out[base + 128] = (float)(r1 < 0 ? 0 : r1); }
}

extern "C" void kernel_launch(void* const* d_in, const int* in_sizes, int n_in,
                              void* d_out, int out_size, void* d_ws, size_t ws_size,
                              hipStream_t stream) {
    const float* input  = (const float*)d_in[0];   // [4,32,32,64]
    const float* kernel = (const float*)d_in[1];   // [3,3,64,128]
    const float* bias   = (const float*)d_in[2];   // [128]
    // d_in[3] = bits (==4, baked into the closed form)

    uint32_t* ws = (uint32_t*)d_ws;                // 36864 + 147968 dwords used

    prep_all<<<144 + 579, 256, 0, stream>>>(kernel, input, ws);
    conv_main<<<2048, 128, 0, stream>>>(ws, bias, (float*)d_out);
}